// Round 12
// baseline (128.108 us; speedup 1.0000x reference)
//
#include <hip/hip_runtime.h>
#include <hip/hip_bf16.h>
#include <cstdint>

// B=4, S=2048, E=1024, H=16, D=64, SCALE = 1/8
#define SCALE_F 0.125f

typedef __attribute__((ext_vector_type(8))) short bf16x8;
typedef __attribute__((ext_vector_type(4))) float f32x4;
typedef __attribute__((ext_vector_type(4))) unsigned short u16x4;
typedef __attribute__((ext_vector_type(8))) unsigned short u16x8;

typedef const __attribute__((address_space(1))) void glb_void;
typedef __attribute__((address_space(3))) void lds_void;

static __device__ __forceinline__ unsigned short f2bf(float f) {
  unsigned u = __builtin_bit_cast(unsigned, f);
  u = (u + 0x7fffu + ((u >> 16) & 1u)) >> 16;
  return (unsigned short)u;
}
static __device__ __forceinline__ float bf2f(unsigned short s) {
  unsigned u = ((unsigned)s) << 16;
  return __builtin_bit_cast(float, u);
}

// chunked XCD swizzle (bijective: all our GEMM grids are multiples of 8)
static __device__ __forceinline__ int xcd_work(int bid, int nwg) {
  int cpx = nwg >> 3;
  return (bid & 7) * cpx + (bid >> 3);
}

// ---------------- prep_x: x[8192][1024] -> xb (bf16) + xT (transposed bf16) ----------------
__global__ __launch_bounds__(256) void prep_x(const float* __restrict__ x,
                                              unsigned short* __restrict__ xb,
                                              unsigned short* __restrict__ xT) {
  __shared__ unsigned short lds[64][72];
  const int t = threadIdx.x;
  const int bid = blockIdx.x;
  const int r0 = (bid & 127) * 64, c0 = (bid >> 7) * 64;
#pragma unroll
  for (int pass = 0; pass < 4; ++pass) {
    int r = pass * 16 + (t >> 4);
    int c = (t & 15) * 4;
    float4 v = *(const float4*)(x + (size_t)(r0 + r) * 1024 + c0 + c);
    u16x4 o = { f2bf(v.x), f2bf(v.y), f2bf(v.z), f2bf(v.w) };
    *(u16x4*)(xb + (size_t)(r0 + r) * 1024 + c0 + c) = o;
#pragma unroll
    for (int j = 0; j < 4; ++j) {
      int C = c + j;
      lds[C][r ^ ((C & 7) << 3)] = o[j];
    }
  }
  __syncthreads();
#pragma unroll
  for (int pass = 0; pass < 2; ++pass) {
    int rr = pass * 32 + (t >> 3);
    int cc = (t & 7) * 8;
    u16x8 v = *(const u16x8*)&lds[rr][cc ^ ((rr & 7) << 3)];
    *(u16x8*)(xT + (size_t)(c0 + rr) * 8192 + r0 + cc) = v;
  }
}

// ---------------- mirror_w: G mirror+reduce (144 blocks) + all weight converts ----------------
__global__ __launch_bounds__(256) void mirror_w(const unsigned short* __restrict__ Gp,
                                                unsigned short* __restrict__ G,
                                                const float* __restrict__ wqkv,
                                                const float* __restrict__ wo,
                                                unsigned short* __restrict__ wqt,
                                                unsigned short* __restrict__ wk,
                                                unsigned short* __restrict__ wv,
                                                unsigned short* __restrict__ wob) {
  __shared__ unsigned short ldsT[128][128];
  __shared__ unsigned short lds[64][72];
  const int t = threadIdx.x;
  const int bid = blockIdx.x;

  if (bid < 144) {
    int ti = bid % 36;
    const int b = bid / 36;
    int mt = 0, accum = 0;
    while (accum + mt + 1 <= ti) { accum += mt + 1; ++mt; }
    int nt = ti - accum;
    const int m0 = mt * 128, n0 = nt * 128;
    const unsigned short* base = Gp + (size_t)b * 4 * 1048576;
    unsigned short* Gb = G + (size_t)b * 1048576;

#pragma unroll
    for (int pass = 0; pass < 8; ++pass) {
      int idx = pass * 2048 + t * 8;
      int r = idx >> 7, c = idx & 127;
      float s[8] = {};
#pragma unroll
      for (int p = 0; p < 4; ++p) {
        u16x8 v = *(const u16x8*)(base + (size_t)p * 1048576 + (size_t)(m0 + r) * 1024 + n0 + c);
#pragma unroll
        for (int j = 0; j < 8; ++j) s[j] += bf2f(v[j]);
      }
      u16x8 o;
#pragma unroll
      for (int j = 0; j < 8; ++j) o[j] = f2bf(s[j]);
      *(u16x8*)(Gb + (size_t)(m0 + r) * 1024 + n0 + c) = o;
#pragma unroll
      for (int j = 0; j < 8; ++j) {
        int col = c + j;
        ldsT[col][r ^ (((col >> 3) & 7) << 3)] = o[j];
      }
    }
    if (mt != nt) {
      __syncthreads();
#pragma unroll
      for (int pass = 0; pass < 8; ++pass) {
        int idx = pass * 2048 + t * 8;
        int rr = idx >> 7, cc = idx & 127;
        u16x8 v = *(const u16x8*)&ldsT[rr][cc ^ (((rr >> 3) & 7) << 3)];
        *(u16x8*)(Gb + (size_t)(n0 + rr) * 1024 + m0 + cc) = v;
      }
    }
  } else if (bid < 3216) {
    int row = bid - 144;             // 0..3071
    const float* src;
    unsigned short* dst;
    if (row < 1024) {
      int h = row >> 6, k = row & 63;
      src = wqkv + (size_t)(h * 192 + 64 + k) * 1024;
      dst = wk + (size_t)row * 1024;
    } else if (row < 2048) {
      int local = row - 1024;
      int h = local >> 6, k = local & 63;
      src = wqkv + (size_t)(h * 192 + 128 + k) * 1024;
      dst = wv + (size_t)local * 1024;
    } else {
      int local = row - 2048;
      src = wo + (size_t)local * 1024;
      dst = wob + (size_t)local * 1024;
    }
    float4 v = *(const float4*)(src + t * 4);
    u16x4 o = { f2bf(v.x), f2bf(v.y), f2bf(v.z), f2bf(v.w) };
    *(u16x4*)(dst + t * 4) = o;
  } else {
    int tid = bid - 3216;            // 0..255
    const int r0 = (tid & 15) * 64, c0 = (tid >> 4) * 64;
#pragma unroll
    for (int pass = 0; pass < 4; ++pass) {
      int r = pass * 16 + (t >> 4);
      int c = (t & 15) * 4;
      int gr = r0 + r;
      int srcRow = (gr >> 6) * 192 + (gr & 63);
      float4 v = *(const float4*)(wqkv + (size_t)srcRow * 1024 + c0 + c);
      lds[c + 0][r] = f2bf(v.x);
      lds[c + 1][r] = f2bf(v.y);
      lds[c + 2][r] = f2bf(v.z);
      lds[c + 3][r] = f2bf(v.w);
    }
    __syncthreads();
#pragma unroll
    for (int pass = 0; pass < 2; ++pass) {
      int rr = pass * 32 + (t >> 3);
      int cc = (t & 7) * 8;
      *(u16x8*)(wqt + (size_t)(c0 + rr) * 1024 + r0 + cc) = *(const u16x8*)&lds[rr][cc];
    }
  }
}

// ---------------- bt GEMM (Weff): 8 waves 64x32, 3-buffer counted-vmcnt, XOR-swizzle ----------------
template<bool F32OUT>
__global__ __launch_bounds__(512) void gemm_bt(const unsigned short* __restrict__ A, int lda,
                                               long aB, long aP,
                                               const unsigned short* __restrict__ Bm, int ldb,
                                               long bB, long bP,
                                               void* __restrict__ Cv, int ldc,
                                               long cB, long cP,
                                               int K, int psplit, int nx, int ny) {
  constexpr int BUF = 128 * 32;   // shorts per buffer
  __shared__ __align__(16) unsigned short Ash[3 * BUF];
  __shared__ __align__(16) unsigned short Bsh[3 * BUF];
  const int work = xcd_work(blockIdx.x, gridDim.x);
  const int xt = work % nx;
  const int yt = (work / nx) % ny;
  const int z  = work / (nx * ny);
  const int bb = z / psplit, pp = z % psplit;
  A  += (size_t)bb * aB + (size_t)pp * aP;
  Bm += (size_t)bb * bB + (size_t)pp * bP;
  const int t = threadIdx.x;
  const int w = t >> 6, l = t & 63;
  const int lr = l & 15, lk = l >> 4;
  const int m0 = yt * 128, n0 = xt * 128;
  const int wr = (w >> 2) * 64, wc = (w & 3) * 32;
  const int srow = t >> 2;
  const int skc = ((t & 3) ^ ((srow >> 1) & 3)) << 3;
  const size_t aOff = (size_t)(m0 + srow) * lda + skc;
  const size_t bOff = (size_t)(n0 + srow) * ldb + skc;
  const int fxor = ((lk ^ ((lr >> 1) & 3)) << 3);
  f32x4 acc[4][2] = {};
  const int nt = K >> 5;

  __builtin_amdgcn_global_load_lds((glb_void*)(A + aOff),       (lds_void*)(Ash + w * 512), 16, 0, 0);
  __builtin_amdgcn_global_load_lds((glb_void*)(Bm + bOff),      (lds_void*)(Bsh + w * 512), 16, 0, 0);
  __builtin_amdgcn_global_load_lds((glb_void*)(A + aOff + 32),  (lds_void*)(Ash + BUF + w * 512), 16, 0, 0);
  __builtin_amdgcn_global_load_lds((glb_void*)(Bm + bOff + 32), (lds_void*)(Bsh + BUF + w * 512), 16, 0, 0);

  unsigned oC = 0, oN = BUF, oT = 2 * BUF;
  for (int it = 0; it < nt; ++it) {
    if (it < nt - 1) asm volatile("s_waitcnt vmcnt(2)" ::: "memory");
    else             asm volatile("s_waitcnt vmcnt(0)" ::: "memory");
    __builtin_amdgcn_s_barrier();
    if (it + 2 < nt) {
      const int kk = (it + 2) << 5;
      __builtin_amdgcn_global_load_lds((glb_void*)(A + aOff + kk),
                                       (lds_void*)(Ash + oT + w * 512), 16, 0, 0);
      __builtin_amdgcn_global_load_lds((glb_void*)(Bm + bOff + kk),
                                       (lds_void*)(Bsh + oT + w * 512), 16, 0, 0);
    }
    bf16x8 af[4], bfv[2];
#pragma unroll
    for (int mi = 0; mi < 4; ++mi)
      af[mi] = *(const bf16x8*)(Ash + oC + (wr + mi * 16 + lr) * 32 + fxor);
#pragma unroll
    for (int ni = 0; ni < 2; ++ni)
      bfv[ni] = *(const bf16x8*)(Bsh + oC + (wc + ni * 16 + lr) * 32 + fxor);
#pragma unroll
    for (int mi = 0; mi < 4; ++mi)
#pragma unroll
      for (int ni = 0; ni < 2; ++ni)
        acc[mi][ni] = __builtin_amdgcn_mfma_f32_16x16x32_bf16(af[mi], bfv[ni], acc[mi][ni], 0, 0, 0);
    unsigned tmp = oC; oC = oN; oN = oT; oT = tmp;
  }

#pragma unroll
  for (int mi = 0; mi < 4; ++mi)
#pragma unroll
    for (int ni = 0; ni < 2; ++ni)
#pragma unroll
      for (int r = 0; r < 4; ++r) {
        const size_t row = (size_t)(m0 + wr + mi * 16 + lk * 4 + r);
        const size_t col = (size_t)(n0 + wc + ni * 16 + lr);
        if constexpr (F32OUT)
          ((float*)Cv)[(size_t)bb * cB + (size_t)pp * cP + row * ldc + col] = acc[mi][ni][r];
        else
          ((unsigned short*)Cv)[(size_t)bb * cB + (size_t)pp * cP + row * ldc + col] = f2bf(acc[mi][ni][r]);
      }
}

// ---------------- gemm_out: out = xb @ Weff^T; BM=128 BN=256, 8 waves of 64x64,
// 3-buffer counted-vmcnt pipeline (fat tile + counted vmcnt COMBO) ----------------
__global__ __launch_bounds__(512) void gemm_out(const unsigned short* __restrict__ xb,
                                                const unsigned short* __restrict__ Weff,
                                                float* __restrict__ outp) {
  constexpr int ABUF = 128 * 32;   // shorts
  constexpr int BBUF = 256 * 32;
  __shared__ __align__(16) unsigned short Ash[3 * ABUF];   // 24 KB
  __shared__ __align__(16) unsigned short Bsh[3 * BBUF];   // 48 KB
  const int work = xcd_work(blockIdx.x, gridDim.x);        // grid 256
  const int xt = work & 3;           // n-tile (256 wide)
  const int yt = work >> 2;          // 0..63 m-tile (128 rows, batch = yt>>4)
  const int b  = yt >> 4;
  const unsigned short* Bm = Weff + (size_t)b * 1048576;
  const int t = threadIdx.x;
  const int w = t >> 6, l = t & 63;
  const int lr = l & 15, lk = l >> 4;
  const int m0 = yt * 128, n0 = xt * 256;
  const int wr = (w >> 2) * 64, wc = (w & 3) * 64;
  // staging: A 1 load/thread (rows 0..127); B 2 loads/thread (rows 0..127, 128..255)
  const int r0 = t >> 2;
  const int s0 = ((t & 3) ^ ((r0 >> 1) & 3)) << 3;
  const int r1 = 128 + r0;
  const int s1 = ((t & 3) ^ ((r1 >> 1) & 3)) << 3;
  const size_t aOff  = (size_t)(m0 + r0) * 1024 + s0;
  const size_t bOff0 = (size_t)(n0 + r0) * 1024 + s0;
  const size_t bOff1 = (size_t)(n0 + r1) * 1024 + s1;
  const int fxor = ((lk ^ ((lr >> 1) & 3)) << 3);
  f32x4 acc[4][4] = {};
  const int nt = 32;   // K=1024 / 32

  // prologue: tiles 0,1 in flight (3 loads/thread each)
#pragma unroll
  for (int pt = 0; pt < 2; ++pt) {
    const int kk = pt << 5;
    __builtin_amdgcn_global_load_lds((glb_void*)(xb + aOff + kk),
                                     (lds_void*)(Ash + pt * ABUF + w * 512), 16, 0, 0);
    __builtin_amdgcn_global_load_lds((glb_void*)(Bm + bOff0 + kk),
                                     (lds_void*)(Bsh + pt * BBUF + w * 512), 16, 0, 0);
    __builtin_amdgcn_global_load_lds((glb_void*)(Bm + bOff1 + kk),
                                     (lds_void*)(Bsh + pt * BBUF + 4096 + w * 512), 16, 0, 0);
  }

  unsigned aC = 0, aN = ABUF, aT = 2 * ABUF;
  unsigned bC = 0, bN = BBUF, bT = 2 * BBUF;
  for (int it = 0; it < nt; ++it) {
    if (it < nt - 1) asm volatile("s_waitcnt vmcnt(3)" ::: "memory");
    else             asm volatile("s_waitcnt vmcnt(0)" ::: "memory");
    __builtin_amdgcn_s_barrier();
    if (it + 2 < nt) {
      const int kk = (it + 2) << 5;
      __builtin_amdgcn_global_load_lds((glb_void*)(xb + aOff + kk),
                                       (lds_void*)(Ash + aT + w * 512), 16, 0, 0);
      __builtin_amdgcn_global_load_lds((glb_void*)(Bm + bOff0 + kk),
                                       (lds_void*)(Bsh + bT + w * 512), 16, 0, 0);
      __builtin_amdgcn_global_load_lds((glb_void*)(Bm + bOff1 + kk),
                                       (lds_void*)(Bsh + bT + 4096 + w * 512), 16, 0, 0);
    }
    bf16x8 af[4], bfv[4];
#pragma unroll
    for (int mi = 0; mi < 4; ++mi)
      af[mi] = *(const bf16x8*)(Ash + aC + (wr + mi * 16 + lr) * 32 + fxor);
#pragma unroll
    for (int ni = 0; ni < 4; ++ni)
      bfv[ni] = *(const bf16x8*)(Bsh + bC + (wc + ni * 16 + lr) * 32 + fxor);
#pragma unroll
    for (int mi = 0; mi < 4; ++mi)
#pragma unroll
      for (int ni = 0; ni < 4; ++ni)
        acc[mi][ni] = __builtin_amdgcn_mfma_f32_16x16x32_bf16(af[mi], bfv[ni], acc[mi][ni], 0, 0, 0);
    unsigned ta = aC; aC = aN; aN = aT; aT = ta;
    unsigned tb = bC; bC = bN; bN = bT; bT = tb;
  }

#pragma unroll
  for (int mi = 0; mi < 4; ++mi)
#pragma unroll
    for (int ni = 0; ni < 4; ++ni)
#pragma unroll
      for (int r = 0; r < 4; ++r)
        outp[(size_t)(m0 + wr + mi * 16 + lk * 4 + r) * 1024 + n0 + wc + ni * 16 + lr]
            = acc[mi][ni][r];
}

// ---------------- triangular Gram GEMM: 4 waves 64x64, 3-buffer pipeline, K=512 ----------------
__global__ __launch_bounds__(256) void gemm_tri(const unsigned short* __restrict__ xT,
                                                unsigned short* __restrict__ Gp) {
  constexpr int BUF = 128 * 32;
  __shared__ __align__(16) unsigned short Ash[3 * BUF];
  __shared__ __align__(16) unsigned short Bsh[3 * BUF];
  const int work = xcd_work(blockIdx.x, gridDim.x);
  int ti = work % 36;
  const int z = work / 36;
  int mt = 0, accum = 0;
  while (accum + mt + 1 <= ti) { accum += mt + 1; ++mt; }
  int nt_ = ti - accum;
  const int b = z >> 2, p = z & 3;
  const unsigned short* base = xT + (size_t)b * 2048 + (size_t)p * 512;

  const int t = threadIdx.x;
  const int w = t >> 6, l = t & 63;
  const int lr = l & 15, lk = l >> 4;
  const int m0 = mt * 128, n0 = nt_ * 128;
  const int wr = (w >> 1) * 64, wc = (w & 1) * 64;
  const int c0i = t, c1i = 256 + t;
  const int r0s = c0i >> 2, r1s = c1i >> 2;
  const int s0 = ((c0i & 3) ^ ((r0s >> 1) & 3)) << 3;
  const int s1 = ((c1i & 3) ^ ((r1s >> 1) & 3)) << 3;
  const size_t a0 = (size_t)(m0 + r0s) * 8192 + s0, a1 = (size_t)(m0 + r1s) * 8192 + s1;
  const size_t b0 = (size_t)(n0 + r0s) * 8192 + s0, b1 = (size_t)(n0 + r1s) * 8192 + s1;
  const int fxor = ((lk ^ ((lr >> 1) & 3)) << 3);
  f32x4 acc[4][4] = {};
  const int NT = 16;   // 512/32

#pragma unroll
  for (int pt = 0; pt < 2; ++pt) {
    const int kk = pt << 5;
    const unsigned off = pt * BUF;
    __builtin_amdgcn_global_load_lds((glb_void*)(base + a0 + kk), (lds_void*)(Ash + off + w * 512), 16, 0, 0);
    __builtin_amdgcn_global_load_lds((glb_void*)(base + a1 + kk), (lds_void*)(Ash + off + 2048 + w * 512), 16, 0, 0);
    __builtin_amdgcn_global_load_lds((glb_void*)(base + b0 + kk), (lds_void*)(Bsh + off + w * 512), 16, 0, 0);
    __builtin_amdgcn_global_load_lds((glb_void*)(base + b1 + kk), (lds_void*)(Bsh + off + 2048 + w * 512), 16, 0, 0);
  }

  unsigned oC = 0, oN = BUF, oT = 2 * BUF;
  for (int it = 0; it < NT; ++it) {
    if (it < NT - 1) asm volatile("s_waitcnt vmcnt(4)" ::: "memory");
    else             asm volatile("s_waitcnt vmcnt(0)" ::: "memory");
    __builtin_amdgcn_s_barrier();
    if (it + 2 < NT) {
      const int kk = (it + 2) << 5;
      __builtin_amdgcn_global_load_lds((glb_void*)(base + a0 + kk), (lds_void*)(Ash + oT + w * 512), 16, 0, 0);
      __builtin_amdgcn_global_load_lds((glb_void*)(base + a1 + kk), (lds_void*)(Ash + oT + 2048 + w * 512), 16, 0, 0);
      __builtin_amdgcn_global_load_lds((glb_void*)(base + b0 + kk), (lds_void*)(Bsh + oT + w * 512), 16, 0, 0);
      __builtin_amdgcn_global_load_lds((glb_void*)(base + b1 + kk), (lds_void*)(Bsh + oT + 2048 + w * 512), 16, 0, 0);
    }
    bf16x8 af[4], bfv[4];
#pragma unroll
    for (int mi = 0; mi < 4; ++mi)
      af[mi] = *(const bf16x8*)(Ash + oC + (wr + mi * 16 + lr) * 32 + fxor);
#pragma unroll
    for (int ni = 0; ni < 4; ++ni)
      bfv[ni] = *(const bf16x8*)(Bsh + oC + (wc + ni * 16 + lr) * 32 + fxor);
#pragma unroll
    for (int mi = 0; mi < 4; ++mi)
#pragma unroll
      for (int ni = 0; ni < 4; ++ni)
        acc[mi][ni] = __builtin_amdgcn_mfma_f32_16x16x32_bf16(af[mi], bfv[ni], acc[mi][ni], 0, 0, 0);
    unsigned tmp = oC; oC = oN; oN = oT; oT = tmp;
  }

  unsigned short* outb = Gp + (size_t)z * 1048576;
#pragma unroll
  for (int mi = 0; mi < 4; ++mi)
#pragma unroll
    for (int ni = 0; ni < 4; ++ni)
#pragma unroll
      for (int r = 0; r < 4; ++r)
        outb[(size_t)(m0 + wr + mi * 16 + lk * 4 + r) * 1024 + n0 + wc + ni * 16 + lr]
            = f2bf(acc[mi][ni][r]);
}

// ---------------- mdirect: Mp[bh][es] = wk_h @ G_b[e-slice] then @ wv_h-slice^T ----------------
__global__ __launch_bounds__(512) void mdirect(const unsigned short* __restrict__ wk,
                                               const unsigned short* __restrict__ G,
                                               const unsigned short* __restrict__ wv,
                                               float* __restrict__ Mp) {
  __shared__ __align__(16) unsigned short Awk[2][64 * 32];
  __shared__ __align__(16) unsigned short Bg[2][128 * 32];
  __shared__ __align__(16) unsigned short Ut[64 * 128];
  __shared__ __align__(16) unsigned short WvS[64 * 128];
  const int work = xcd_work(blockIdx.x, gridDim.x);
  const int bh = work >> 3, es = work & 7;
  const int b = bh >> 4, h = bh & 15;
  const int e0 = es * 128;
  const int t = threadIdx.x;
  const int w = t >> 6, l = t & 63;
  const int lr = l & 15, lk = l >> 4;

  const unsigned short* wkB = wk + (size_t)(h * 64) * 1024;
  const unsigned short* Gb  = G + (size_t)b * 1048576 + (size_t)e0 * 1024;
  const unsigned short* wvB = wv + (size_t)(h * 64) * 1024 + e0;

  const int arow = t >> 2, askc = ((t & 3) ^ ((arow >> 1) & 3)) << 3;
  const int brow = t >> 2, bskc = ((t & 3) ^ ((brow >> 1) & 3)) << 3;
  const size_t aOff = (size_t)arow * 1024 + askc;
  const size_t bOff = (size_t)brow * 1024 + bskc;
  const int fxor = ((lk ^ ((lr >> 1) & 3)) << 3);

#pragma unroll
  for (int i = 0; i < 2; ++i) {
    int idx = i * 512 + t;
    int row = idx >> 4, slot = idx & 15;
    int sslot = slot ^ (row & 15);
    __builtin_amdgcn_global_load_lds(
        (glb_void*)(wvB + (size_t)row * 1024 + sslot * 8),
        (lds_void*)(WvS + i * 4096 + w * 512), 16, 0, 0);
  }
  if (t < 256)
    __builtin_amdgcn_global_load_lds((glb_void*)(wkB + aOff),
                                     (lds_void*)(Awk[0] + w * 512), 16, 0, 0);
  __builtin_amdgcn_global_load_lds((glb_void*)(Gb + bOff),
                                   (lds_void*)(Bg[0] + w * 512), 16, 0, 0);
  __syncthreads();

  const int wc = w * 16;
  f32x4 acc[4] = {};
  int cur = 0;
  for (int k0 = 0; k0 < 1024; k0 += 32, cur ^= 1) {
    if (k0 + 32 < 1024) {
      if (t < 256)
        __builtin_amdgcn_global_load_lds((glb_void*)(wkB + aOff + k0 + 32),
                                         (lds_void*)(Awk[cur ^ 1] + w * 512), 16, 0, 0);
      __builtin_amdgcn_global_load_lds((glb_void*)(Gb + bOff + k0 + 32),
                                       (lds_void*)(Bg[cur ^ 1] + w * 512), 16, 0, 0);
    }
    bf16x8 af[4], bfv;
#pragma unroll
    for (int mi = 0; mi < 4; ++mi)
      af[mi] = *(const bf16x8*)(Awk[cur] + (mi * 16 + lr) * 32 + fxor);
    bfv = *(const bf16x8*)(Bg[cur] + (wc + lr) * 32 + fxor);
#pragma unroll
    for (int mi = 0; mi < 4; ++mi)
      acc[mi] = __builtin_amdgcn_mfma_f32_16x16x32_bf16(af[mi], bfv, acc[mi], 0, 0, 0);
    __syncthreads();
  }

#pragma unroll
  for (int mi = 0; mi < 4; ++mi)
#pragma unroll
    for (int r = 0; r < 4; ++r) {
      int i = mi * 16 + lk * 4 + r;
      int col = wc + lr;
      int addr = i * 128 + ((((col >> 3) ^ (i & 15)) << 3) | (col & 7));
      Ut[addr] = f2bf(acc[mi][r]);
    }
  __syncthreads();

  if (w < 4) {
    f32x4 acc2[4] = {};
#pragma unroll
    for (int ks = 0; ks < 4; ++ks) {
      int slot = (ks << 2) | lk;
      bf16x8 a2 = *(const bf16x8*)(Ut + (w * 16 + lr) * 128 + ((slot ^ lr) << 3));
      bf16x8 b2[4];
#pragma unroll
      for (int ni = 0; ni < 4; ++ni)
        b2[ni] = *(const bf16x8*)(WvS + (ni * 16 + lr) * 128 + ((slot ^ lr) << 3));
#pragma unroll
      for (int ni = 0; ni < 4; ++ni)
        acc2[ni] = __builtin_amdgcn_mfma_f32_16x16x32_bf16(a2, b2[ni], acc2[ni], 0, 0, 0);
    }
    float* outp = Mp + ((size_t)bh * 8 + es) * 4096;
#pragma unroll
    for (int ni = 0; ni < 4; ++ni)
#pragma unroll
      for (int r = 0; r < 4; ++r)
        outp[(w * 16 + lk * 4 + r) * 64 + ni * 16 + lr] = acc2[ni][r];
  }
}

// ---------------- fused: reduce Mp (8 partials) -> Mt (LDS) -> Amat slice ----------------
__global__ __launch_bounds__(256) void amat_fused(const float* __restrict__ Mp,
                                                  const unsigned short* __restrict__ wqt,
                                                  unsigned short* __restrict__ Amat) {
  __shared__ float Msh[64 * 68];
  __shared__ unsigned short MtSh[64][80];
  const int t = threadIdx.x;
  const int et = blockIdx.x, bh = blockIdx.y;
  const int b = bh >> 4, h = bh & 15;

  const float* base = Mp + (size_t)bh * 32768;
  for (int i = t * 4; i < 4096; i += 1024) {
    float4 s = *(const float4*)(base + i);
#pragma unroll
    for (int p = 1; p < 8; ++p) {
      float4 v = *(const float4*)(base + p * 4096 + i);
      s.x += v.x; s.y += v.y; s.z += v.z; s.w += v.w;
    }
    int k = i >> 6, dp = i & 63;
    *(float4*)&Msh[k * 68 + dp] = s;
  }
  __syncthreads();

  for (int i = t; i < 4096; i += 256) {
    int dp = i >> 6, k = i & 63;
    MtSh[dp][k] = f2bf(Msh[k * 68 + dp] * SCALE_F);
  }
  __syncthreads();

  const int w = t >> 6, l = t & 63;
  const int lr = l & 15, lk = l >> 4;
  const int e0 = et * 128 + w * 32;

  f32x4 acc[2][4] = {};
#pragma unroll
  for (int ks = 0; ks < 2; ++ks) {
    bf16x8 af[2], bfv[4];
#pragma unroll
    for (int mi = 0; mi < 2; ++mi)
      af[mi] = *(const bf16x8*)(wqt + (size_t)(e0 + mi * 16 + lr) * 1024 + h * 64 + ks * 32 + lk * 8);
#pragma unroll
    for (int ni = 0; ni < 4; ++ni)
      bfv[ni] = *(const bf16x8*)(&MtSh[ni * 16 + lr][ks * 32 + lk * 8]);
#pragma unroll
    for (int mi = 0; mi < 2; ++mi)
#pragma unroll
      for (int ni = 0; ni < 4; ++ni)
        acc[mi][ni] = __builtin_amdgcn_mfma_f32_16x16x32_bf16(af[mi], bfv[ni], acc[mi][ni], 0, 0, 0);
  }
#pragma unroll
  for (int mi = 0; mi < 2; ++mi)
#pragma unroll
    for (int ni = 0; ni < 4; ++ni)
#pragma unroll
      for (int r = 0; r < 4; ++r)
        Amat[(size_t)b * 1048576 + (size_t)(e0 + mi * 16 + lk * 4 + r) * 1024 + h * 64 + ni * 16 + lr]
            = f2bf(acc[mi][ni][r]);
}

// ---------------- launch ----------------
extern "C" void kernel_launch(void* const* d_in, const int* in_sizes, int n_in,
                              void* d_out, int out_size, void* d_ws, size_t ws_size,
                              hipStream_t stream) {
  const float* x    = (const float*)d_in[0];   // [4,2048,1024]
  const float* wqkv = (const float*)d_in[1];   // [3072,1024]
  const float* wo   = (const float*)d_in[2];   // [1024,1024]
  float* out = (float*)d_out;                  // [4,2048,1024] fp32

  char* ws = (char*)d_ws;
  const size_t MB = 1048576;
  unsigned short* xb   = (unsigned short*)(ws + 0);        // 16MB [8192][1024]
  unsigned short* xT   = (unsigned short*)(ws + 16 * MB);  // 16MB [1024][8192]
  unsigned short* wqt  = (unsigned short*)(ws + 32 * MB);  // 2MB
  unsigned short* wk   = (unsigned short*)(ws + 34 * MB);  // 2MB
  unsigned short* wv   = (unsigned short*)(ws + 36 * MB);  // 2MB
  unsigned short* wob  = (unsigned short*)(ws + 38 * MB);  // 2MB
  unsigned short* Gp   = (unsigned short*)(ws + 40 * MB);  // 32MB [4b][4p][1024][1024] (lower tiles)
  unsigned short* G    = (unsigned short*)(ws + 72 * MB);  // 8MB  [4b][1024][1024]  -> peak 80MB
  // reuse dead regions (Gp dead after mirror_w):
  float*          Mp   = (float*)        (ws + 40 * MB);   // 8MB  [64 bh][8 es][64][64] f32
  unsigned short* Amat = (unsigned short*)(ws + 48 * MB);  // 8MB  [4b][1024 e][1024 i]
  unsigned short* Weff = (unsigned short*)(ws + 56 * MB);  // 8MB  [4b][1024 j][1024 e]

  const long M1 = 1048576;

  // x converts
  prep_x<<<2048, 256, 0, stream>>>(x, xb, xT);

  // G_b = x_b^T x_b : lower triangle, split-K x4 (576 blocks, 4 waves 64x64, 3-buf pipeline)
  gemm_tri<<<576, 256, 0, stream>>>(xT, Gp);

  // mirror+reduce G (144 blocks) + ALL weight converts in one launch
  mirror_w<<<3472, 256, 0, stream>>>(Gp, G, wqkv, wo, wqt, wk, wv, wob);

  // M partials directly: Mp[bh][es] = (wk_h @ G_b[e-slice]) @ wv_h-slice^T   (512 blocks)
  mdirect<<<512, 512, 0, stream>>>(wk, G, wv, Mp);

  // fused: reduce Mp -> Mt -> Amat_b = Wq^T * blockdiag(SCALE*M_b)   (512 blocks)
  amat_fused<<<dim3(8, 64), 256, 0, stream>>>(Mp, wqt, Amat);

  // Weff_b[j][e] = sum_i wo[j][i] * Amat_b[e][i]   (256 blocks, pipelined)
  gemm_bt<false><<<256, 512, 0, stream>>>(wob, 1024, 0, 0,
                                          Amat, 1024, M1, 0,
                                          (void*)Weff, 1024, M1, 0, 1024, 1, 8, 8);

  // out = xb @ Weff^T  (fp32; 256 blocks, BM=128 BN=256, 8 waves of 64x64, counted-vmcnt)
  gemm_out<<<256, 512, 0, stream>>>(xb, Weff, out);
}

// Round 13
// 122.629 us; speedup vs baseline: 1.0447x; 1.0447x over previous
//
#include <hip/hip_runtime.h>
#include <hip/hip_bf16.h>
#include <cstdint>

// B=4, S=2048, E=1024, H=16, D=64, SCALE = 1/8
#define SCALE_F 0.125f

typedef __attribute__((ext_vector_type(8))) short bf16x8;
typedef __attribute__((ext_vector_type(4))) float f32x4;
typedef __attribute__((ext_vector_type(4))) unsigned short u16x4;
typedef __attribute__((ext_vector_type(8))) unsigned short u16x8;

typedef const __attribute__((address_space(1))) void glb_void;
typedef __attribute__((address_space(3))) void lds_void;

static __device__ __forceinline__ unsigned short f2bf(float f) {
  unsigned u = __builtin_bit_cast(unsigned, f);
  u = (u + 0x7fffu + ((u >> 16) & 1u)) >> 16;
  return (unsigned short)u;
}
static __device__ __forceinline__ float bf2f(unsigned short s) {
  unsigned u = ((unsigned)s) << 16;
  return __builtin_bit_cast(float, u);
}

// chunked XCD swizzle (bijective: all our GEMM grids are multiples of 8)
static __device__ __forceinline__ int xcd_work(int bid, int nwg) {
  int cpx = nwg >> 3;
  return (bid & 7) * cpx + (bid >> 3);
}

// ---------------- fused prep: all converts in ONE kernel ----------------
__global__ __launch_bounds__(256) void prep(const float* __restrict__ x,
                                            const float* __restrict__ wqkv,
                                            const float* __restrict__ wo,
                                            unsigned short* __restrict__ xb,
                                            unsigned short* __restrict__ xT,
                                            unsigned short* __restrict__ wqt,
                                            unsigned short* __restrict__ wk,
                                            unsigned short* __restrict__ wv,
                                            unsigned short* __restrict__ wob) {
  __shared__ unsigned short lds[64][72];
  const int t = threadIdx.x;
  const int bid = blockIdx.x;

  if (bid < 2048) {
    // ---- cvt_x: x[8192][1024] -> xb + xT ----
    const int r0 = (bid & 127) * 64, c0 = (bid >> 7) * 64;
#pragma unroll
    for (int pass = 0; pass < 4; ++pass) {
      int r = pass * 16 + (t >> 4);
      int c = (t & 15) * 4;
      float4 v = *(const float4*)(x + (size_t)(r0 + r) * 1024 + c0 + c);
      u16x4 o = { f2bf(v.x), f2bf(v.y), f2bf(v.z), f2bf(v.w) };
      *(u16x4*)(xb + (size_t)(r0 + r) * 1024 + c0 + c) = o;
#pragma unroll
      for (int j = 0; j < 4; ++j) {
        int C = c + j;
        lds[C][r ^ ((C & 7) << 3)] = o[j];
      }
    }
    __syncthreads();
#pragma unroll
    for (int pass = 0; pass < 2; ++pass) {
      int rr = pass * 32 + (t >> 3);
      int cc = (t & 7) * 8;
      u16x8 v = *(const u16x8*)&lds[rr][cc ^ ((rr & 7) << 3)];
      *(u16x8*)(xT + (size_t)(c0 + rr) * 8192 + r0 + cc) = v;
    }
  } else if (bid < 5120) {
    // ---- cvt_w: row gathers ----
    int row = bid - 2048;            // 0..3071
    const float* src;
    unsigned short* dst;
    if (row < 1024) {
      int h = row >> 6, k = row & 63;
      src = wqkv + (size_t)(h * 192 + 64 + k) * 1024;
      dst = wk + (size_t)row * 1024;
    } else if (row < 2048) {
      int local = row - 1024;
      int h = local >> 6, k = local & 63;
      src = wqkv + (size_t)(h * 192 + 128 + k) * 1024;
      dst = wv + (size_t)local * 1024;
    } else {
      int local = row - 2048;
      src = wo + (size_t)local * 1024;
      dst = wob + (size_t)local * 1024;
    }
    float4 v = *(const float4*)(src + t * 4);
    u16x4 o = { f2bf(v.x), f2bf(v.y), f2bf(v.z), f2bf(v.w) };
    *(u16x4*)(dst + t * 4) = o;
  } else {
    // ---- wqt transpose: wqt[e][h*64+k] = bf16(wqkv[h*192+k][e]) ----
    int tid = bid - 5120;            // 0..255
    const int r0 = (tid & 15) * 64, c0 = (tid >> 4) * 64;
#pragma unroll
    for (int pass = 0; pass < 4; ++pass) {
      int r = pass * 16 + (t >> 4);
      int c = (t & 15) * 4;
      int gr = r0 + r;
      int srcRow = (gr >> 6) * 192 + (gr & 63);
      float4 v = *(const float4*)(wqkv + (size_t)srcRow * 1024 + c0 + c);
      lds[c + 0][r] = f2bf(v.x);
      lds[c + 1][r] = f2bf(v.y);
      lds[c + 2][r] = f2bf(v.z);
      lds[c + 3][r] = f2bf(v.w);
    }
    __syncthreads();
#pragma unroll
    for (int pass = 0; pass < 2; ++pass) {
      int rr = pass * 32 + (t >> 3);
      int cc = (t & 7) * 8;
      *(u16x8*)(wqt + (size_t)(c0 + rr) * 1024 + r0 + cc) = *(const u16x8*)&lds[rr][cc];
    }
  }
}

// ---------------- bt GEMM: 8 waves, double-buffered prefetch, XOR-swizzled LDS ----------------
template<bool F32OUT>
__global__ __launch_bounds__(512) void gemm_bt(const unsigned short* __restrict__ A, int lda,
                                               long aB, long aP,
                                               const unsigned short* __restrict__ Bm, int ldb,
                                               long bB, long bP,
                                               void* __restrict__ Cv, int ldc,
                                               long cB, long cP,
                                               int K, int psplit, int nx, int ny) {
  __shared__ __align__(16) unsigned short Ash[2][128 * 32];
  __shared__ __align__(16) unsigned short Bsh[2][128 * 32];
  const int work = xcd_work(blockIdx.x, gridDim.x);
  const int xt = work % nx;
  const int yt = (work / nx) % ny;
  const int z  = work / (nx * ny);
  const int bb = z / psplit, pp = z % psplit;
  A  += (size_t)bb * aB + (size_t)pp * aP;
  Bm += (size_t)bb * bB + (size_t)pp * bP;
  const int t = threadIdx.x;
  const int w = t >> 6, l = t & 63;
  const int lr = l & 15, lk = l >> 4;
  const int m0 = yt * 128, n0 = xt * 128;
  const int wr = (w >> 2) * 64, wc = (w & 3) * 32;
  const int srow = t >> 2;
  const int skc = ((t & 3) ^ ((srow >> 1) & 3)) << 3;
  const size_t aOff = (size_t)(m0 + srow) * lda + skc;
  const size_t bOff = (size_t)(n0 + srow) * ldb + skc;
  const int fxor = ((lk ^ ((lr >> 1) & 3)) << 3);
  f32x4 acc[4][2] = {};

  __builtin_amdgcn_global_load_lds((glb_void*)(A + aOff), (lds_void*)(Ash[0] + w * 512), 16, 0, 0);
  __builtin_amdgcn_global_load_lds((glb_void*)(Bm + bOff), (lds_void*)(Bsh[0] + w * 512), 16, 0, 0);
  __syncthreads();

  int cur = 0;
  for (int k0 = 0; k0 < K; k0 += 32, cur ^= 1) {
    if (k0 + 32 < K) {
      __builtin_amdgcn_global_load_lds((glb_void*)(A + aOff + k0 + 32),
                                       (lds_void*)(Ash[cur ^ 1] + w * 512), 16, 0, 0);
      __builtin_amdgcn_global_load_lds((glb_void*)(Bm + bOff + k0 + 32),
                                       (lds_void*)(Bsh[cur ^ 1] + w * 512), 16, 0, 0);
    }
    bf16x8 af[4], bfv[2];
#pragma unroll
    for (int mi = 0; mi < 4; ++mi)
      af[mi] = *(const bf16x8*)(Ash[cur] + (wr + mi * 16 + lr) * 32 + fxor);
#pragma unroll
    for (int ni = 0; ni < 2; ++ni)
      bfv[ni] = *(const bf16x8*)(Bsh[cur] + (wc + ni * 16 + lr) * 32 + fxor);
#pragma unroll
    for (int mi = 0; mi < 4; ++mi)
#pragma unroll
      for (int ni = 0; ni < 2; ++ni)
        acc[mi][ni] = __builtin_amdgcn_mfma_f32_16x16x32_bf16(af[mi], bfv[ni], acc[mi][ni], 0, 0, 0);
    __syncthreads();
  }

#pragma unroll
  for (int mi = 0; mi < 4; ++mi)
#pragma unroll
    for (int ni = 0; ni < 2; ++ni)
#pragma unroll
      for (int r = 0; r < 4; ++r) {
        const size_t row = (size_t)(m0 + wr + mi * 16 + lk * 4 + r);
        const size_t col = (size_t)(n0 + wc + ni * 16 + lr);
        if constexpr (F32OUT)
          ((float*)Cv)[(size_t)bb * cB + (size_t)pp * cP + row * ldc + col] = acc[mi][ni][r];
        else
          ((unsigned short*)Cv)[(size_t)bb * cB + (size_t)pp * cP + row * ldc + col] = f2bf(acc[mi][ni][r]);
      }
}

// ---------------- triangular Gram GEMM: dbuf+swizzle engine, K=512 ----------------
__global__ __launch_bounds__(512) void gemm_tri(const unsigned short* __restrict__ xT,
                                                unsigned short* __restrict__ Gp) {
  __shared__ __align__(16) unsigned short Ash[2][128 * 32];
  __shared__ __align__(16) unsigned short Bsh[2][128 * 32];
  const int work = xcd_work(blockIdx.x, gridDim.x);
  int ti = work % 36;
  const int z = work / 36;
  int mt = 0, accum = 0;
  while (accum + mt + 1 <= ti) { accum += mt + 1; ++mt; }
  int nt = ti - accum;
  const int b = z >> 2, p = z & 3;
  const unsigned short* base = xT + (size_t)b * 2048 + (size_t)p * 512;

  const int t = threadIdx.x;
  const int w = t >> 6, l = t & 63;
  const int lr = l & 15, lk = l >> 4;
  const int m0 = mt * 128, n0 = nt * 128;
  const int wr = (w >> 2) * 64, wc = (w & 3) * 32;
  const int srow = t >> 2;
  const int skc = ((t & 3) ^ ((srow >> 1) & 3)) << 3;
  const size_t aOff = (size_t)(m0 + srow) * 8192 + skc;
  const size_t bOff = (size_t)(n0 + srow) * 8192 + skc;
  const int fxor = ((lk ^ ((lr >> 1) & 3)) << 3);
  f32x4 acc[4][2] = {};

  __builtin_amdgcn_global_load_lds((glb_void*)(base + aOff), (lds_void*)(Ash[0] + w * 512), 16, 0, 0);
  __builtin_amdgcn_global_load_lds((glb_void*)(base + bOff), (lds_void*)(Bsh[0] + w * 512), 16, 0, 0);
  __syncthreads();

  int cur = 0;
  for (int k0 = 0; k0 < 512; k0 += 32, cur ^= 1) {
    if (k0 + 32 < 512) {
      __builtin_amdgcn_global_load_lds((glb_void*)(base + aOff + k0 + 32),
                                       (lds_void*)(Ash[cur ^ 1] + w * 512), 16, 0, 0);
      __builtin_amdgcn_global_load_lds((glb_void*)(base + bOff + k0 + 32),
                                       (lds_void*)(Bsh[cur ^ 1] + w * 512), 16, 0, 0);
    }
    bf16x8 af[4], bfv[2];
#pragma unroll
    for (int mi = 0; mi < 4; ++mi)
      af[mi] = *(const bf16x8*)(Ash[cur] + (wr + mi * 16 + lr) * 32 + fxor);
#pragma unroll
    for (int ni = 0; ni < 2; ++ni)
      bfv[ni] = *(const bf16x8*)(Bsh[cur] + (wc + ni * 16 + lr) * 32 + fxor);
#pragma unroll
    for (int mi = 0; mi < 4; ++mi)
#pragma unroll
      for (int ni = 0; ni < 2; ++ni)
        acc[mi][ni] = __builtin_amdgcn_mfma_f32_16x16x32_bf16(af[mi], bfv[ni], acc[mi][ni], 0, 0, 0);
    __syncthreads();
  }

  unsigned short* out = Gp + (size_t)z * 1048576;
#pragma unroll
  for (int mi = 0; mi < 4; ++mi)
#pragma unroll
    for (int ni = 0; ni < 2; ++ni)
#pragma unroll
      for (int r = 0; r < 4; ++r)
        out[(size_t)(m0 + wr + mi * 16 + lk * 4 + r) * 1024 + n0 + wc + ni * 16 + lr]
            = f2bf(acc[mi][ni][r]);
}

// ---------------- mirror+reduce via LDS transpose ----------------
__global__ __launch_bounds__(256) void mirror_reduce(const unsigned short* __restrict__ Gp,
                                                     unsigned short* __restrict__ G) {
  __shared__ unsigned short ldsT[128][128];
  int ti = blockIdx.x;
  int mt = 0, accum = 0;
  while (accum + mt + 1 <= ti) { accum += mt + 1; ++mt; }
  int nt = ti - accum;
  const int b = blockIdx.y;
  const int m0 = mt * 128, n0 = nt * 128;
  const unsigned short* base = Gp + (size_t)b * 4 * 1048576;
  unsigned short* Gb = G + (size_t)b * 1048576;
  const int t = threadIdx.x;

#pragma unroll
  for (int pass = 0; pass < 8; ++pass) {
    int idx = pass * 2048 + t * 8;
    int r = idx >> 7, c = idx & 127;
    float s[8] = {};
#pragma unroll
    for (int p = 0; p < 4; ++p) {
      u16x8 v = *(const u16x8*)(base + (size_t)p * 1048576 + (size_t)(m0 + r) * 1024 + n0 + c);
#pragma unroll
      for (int j = 0; j < 8; ++j) s[j] += bf2f(v[j]);
    }
    u16x8 o;
#pragma unroll
    for (int j = 0; j < 8; ++j) o[j] = f2bf(s[j]);
    *(u16x8*)(Gb + (size_t)(m0 + r) * 1024 + n0 + c) = o;
#pragma unroll
    for (int j = 0; j < 8; ++j) {
      int col = c + j;
      ldsT[col][r ^ (((col >> 3) & 7) << 3)] = o[j];
    }
  }

  if (mt != nt) {
    __syncthreads();
#pragma unroll
    for (int pass = 0; pass < 8; ++pass) {
      int idx = pass * 2048 + t * 8;
      int rr = idx >> 7, cc = idx & 127;
      u16x8 v = *(const u16x8*)&ldsT[rr][cc ^ (((rr >> 3) & 7) << 3)];
      *(u16x8*)(Gb + (size_t)(n0 + rr) * 1024 + m0 + cc) = v;
    }
  }
}

// ---------------- mdirect: Mp[bh][es] = wk_h @ G_b[e-slice] then @ wv_h-slice^T ----------------
// grid 512 = (bh 64) x (es 8), 512 threads (8 waves).
__global__ __launch_bounds__(512) void mdirect(const unsigned short* __restrict__ wk,
                                               const unsigned short* __restrict__ G,
                                               const unsigned short* __restrict__ wv,
                                               float* __restrict__ Mp) {
  __shared__ __align__(16) unsigned short Awk[2][64 * 32];
  __shared__ __align__(16) unsigned short Bg[2][128 * 32];
  __shared__ __align__(16) unsigned short Ut[64 * 128];
  __shared__ __align__(16) unsigned short WvS[64 * 128];
  const int work = xcd_work(blockIdx.x, gridDim.x);
  const int bh = work >> 3, es = work & 7;
  const int b = bh >> 4, h = bh & 15;
  const int e0 = es * 128;
  const int t = threadIdx.x;
  const int w = t >> 6, l = t & 63;
  const int lr = l & 15, lk = l >> 4;

  const unsigned short* wkB = wk + (size_t)(h * 64) * 1024;
  const unsigned short* Gb  = G + (size_t)b * 1048576 + (size_t)e0 * 1024;
  const unsigned short* wvB = wv + (size_t)(h * 64) * 1024 + e0;

  const int arow = t >> 2, askc = ((t & 3) ^ ((arow >> 1) & 3)) << 3;
  const int brow = t >> 2, bskc = ((t & 3) ^ ((brow >> 1) & 3)) << 3;
  const size_t aOff = (size_t)arow * 1024 + askc;
  const size_t bOff = (size_t)brow * 1024 + bskc;
  const int fxor = ((lk ^ ((lr >> 1) & 3)) << 3);

#pragma unroll
  for (int i = 0; i < 2; ++i) {
    int idx = i * 512 + t;
    int row = idx >> 4, slot = idx & 15;
    int sslot = slot ^ (row & 15);
    __builtin_amdgcn_global_load_lds(
        (glb_void*)(wvB + (size_t)row * 1024 + sslot * 8),
        (lds_void*)(WvS + i * 4096 + w * 512), 16, 0, 0);
  }
  if (t < 256)
    __builtin_amdgcn_global_load_lds((glb_void*)(wkB + aOff),
                                     (lds_void*)(Awk[0] + w * 512), 16, 0, 0);
  __builtin_amdgcn_global_load_lds((glb_void*)(Gb + bOff),
                                   (lds_void*)(Bg[0] + w * 512), 16, 0, 0);
  __syncthreads();

  const int wc = w * 16;
  f32x4 acc[4] = {};
  int cur = 0;
  for (int k0 = 0; k0 < 1024; k0 += 32, cur ^= 1) {
    if (k0 + 32 < 1024) {
      if (t < 256)
        __builtin_amdgcn_global_load_lds((glb_void*)(wkB + aOff + k0 + 32),
                                         (lds_void*)(Awk[cur ^ 1] + w * 512), 16, 0, 0);
      __builtin_amdgcn_global_load_lds((glb_void*)(Gb + bOff + k0 + 32),
                                       (lds_void*)(Bg[cur ^ 1] + w * 512), 16, 0, 0);
    }
    bf16x8 af[4], bfv;
#pragma unroll
    for (int mi = 0; mi < 4; ++mi)
      af[mi] = *(const bf16x8*)(Awk[cur] + (mi * 16 + lr) * 32 + fxor);
    bfv = *(const bf16x8*)(Bg[cur] + (wc + lr) * 32 + fxor);
#pragma unroll
    for (int mi = 0; mi < 4; ++mi)
      acc[mi] = __builtin_amdgcn_mfma_f32_16x16x32_bf16(af[mi], bfv, acc[mi], 0, 0, 0);
    __syncthreads();
  }

#pragma unroll
  for (int mi = 0; mi < 4; ++mi)
#pragma unroll
    for (int r = 0; r < 4; ++r) {
      int i = mi * 16 + lk * 4 + r;
      int col = wc + lr;
      int addr = i * 128 + ((((col >> 3) ^ (i & 15)) << 3) | (col & 7));
      Ut[addr] = f2bf(acc[mi][r]);
    }
  __syncthreads();

  if (w < 4) {
    f32x4 acc2[4] = {};
#pragma unroll
    for (int ks = 0; ks < 4; ++ks) {
      int slot = (ks << 2) | lk;
      bf16x8 a2 = *(const bf16x8*)(Ut + (w * 16 + lr) * 128 + ((slot ^ lr) << 3));
      bf16x8 b2[4];
#pragma unroll
      for (int ni = 0; ni < 4; ++ni)
        b2[ni] = *(const bf16x8*)(WvS + (ni * 16 + lr) * 128 + ((slot ^ lr) << 3));
#pragma unroll
      for (int ni = 0; ni < 4; ++ni)
        acc2[ni] = __builtin_amdgcn_mfma_f32_16x16x32_bf16(a2, b2[ni], acc2[ni], 0, 0, 0);
    }
    float* out = Mp + ((size_t)bh * 8 + es) * 4096;
#pragma unroll
    for (int ni = 0; ni < 4; ++ni)
#pragma unroll
      for (int r = 0; r < 4; ++r)
        out[(w * 16 + lk * 4 + r) * 64 + ni * 16 + lr] = acc2[ni][r];
  }
}

// ---------------- fused: reduce Mp (8 partials) -> Mt (LDS) -> Amat slice ----------------
__global__ __launch_bounds__(256) void amat_fused(const float* __restrict__ Mp,
                                                  const unsigned short* __restrict__ wqt,
                                                  unsigned short* __restrict__ Amat) {
  __shared__ float Msh[64 * 68];            // [k][dp], padded row 68
  __shared__ unsigned short MtSh[64][80];   // [dp][k], padded row 80
  const int t = threadIdx.x;
  const int et = blockIdx.x, bh = blockIdx.y;
  const int b = bh >> 4, h = bh & 15;

  const float* base = Mp + (size_t)bh * 32768;
  for (int i = t * 4; i < 4096; i += 1024) {
    float4 s = *(const float4*)(base + i);
#pragma unroll
    for (int p = 1; p < 8; ++p) {
      float4 v = *(const float4*)(base + p * 4096 + i);
      s.x += v.x; s.y += v.y; s.z += v.z; s.w += v.w;
    }
    int k = i >> 6, dp = i & 63;
    *(float4*)&Msh[k * 68 + dp] = s;
  }
  __syncthreads();

  for (int i = t; i < 4096; i += 256) {
    int dp = i >> 6, k = i & 63;
    MtSh[dp][k] = f2bf(Msh[k * 68 + dp] * SCALE_F);
  }
  __syncthreads();

  const int w = t >> 6, l = t & 63;
  const int lr = l & 15, lk = l >> 4;
  const int e0 = et * 128 + w * 32;

  f32x4 acc[2][4] = {};
#pragma unroll
  for (int ks = 0; ks < 2; ++ks) {
    bf16x8 af[2], bfv[4];
#pragma unroll
    for (int mi = 0; mi < 2; ++mi)
      af[mi] = *(const bf16x8*)(wqt + (size_t)(e0 + mi * 16 + lr) * 1024 + h * 64 + ks * 32 + lk * 8);
#pragma unroll
    for (int ni = 0; ni < 4; ++ni)
      bfv[ni] = *(const bf16x8*)(&MtSh[ni * 16 + lr][ks * 32 + lk * 8]);
#pragma unroll
    for (int mi = 0; mi < 2; ++mi)
#pragma unroll
      for (int ni = 0; ni < 4; ++ni)
        acc[mi][ni] = __builtin_amdgcn_mfma_f32_16x16x32_bf16(af[mi], bfv[ni], acc[mi][ni], 0, 0, 0);
  }
#pragma unroll
  for (int mi = 0; mi < 2; ++mi)
#pragma unroll
    for (int ni = 0; ni < 4; ++ni)
#pragma unroll
      for (int r = 0; r < 4; ++r)
        Amat[(size_t)b * 1048576 + (size_t)(e0 + mi * 16 + lk * 4 + r) * 1024 + h * 64 + ni * 16 + lr]
            = f2bf(acc[mi][ni][r]);
}

// ---------------- launch ----------------
extern "C" void kernel_launch(void* const* d_in, const int* in_sizes, int n_in,
                              void* d_out, int out_size, void* d_ws, size_t ws_size,
                              hipStream_t stream) {
  const float* x    = (const float*)d_in[0];   // [4,2048,1024]
  const float* wqkv = (const float*)d_in[1];   // [3072,1024]
  const float* wo   = (const float*)d_in[2];   // [1024,1024]
  float* out = (float*)d_out;                  // [4,2048,1024] fp32

  char* ws = (char*)d_ws;
  const size_t MB = 1048576;
  unsigned short* xb   = (unsigned short*)(ws + 0);        // 16MB [8192][1024]
  unsigned short* xT   = (unsigned short*)(ws + 16 * MB);  // 16MB [1024][8192]
  unsigned short* wqt  = (unsigned short*)(ws + 32 * MB);  // 2MB
  unsigned short* wk   = (unsigned short*)(ws + 34 * MB);  // 2MB
  unsigned short* wv   = (unsigned short*)(ws + 36 * MB);  // 2MB
  unsigned short* wob  = (unsigned short*)(ws + 38 * MB);  // 2MB
  unsigned short* Gp   = (unsigned short*)(ws + 40 * MB);  // 32MB [4b][4p][1024][1024] (lower tiles)
  unsigned short* G    = (unsigned short*)(ws + 72 * MB);  // 8MB  [4b][1024][1024]  -> peak 80MB
  // reuse dead regions (Gp dead after mirror_reduce):
  float*          Mp   = (float*)        (ws + 40 * MB);   // 8MB  [64 bh][8 es][64][64] f32
  unsigned short* Amat = (unsigned short*)(ws + 48 * MB);  // 8MB  [4b][1024 e][1024 i]
  unsigned short* Weff = (unsigned short*)(ws + 56 * MB);  // 8MB  [4b][1024 j][1024 e]

  const long M1 = 1048576;

  // all converts in one launch
  prep<<<5376, 256, 0, stream>>>(x, wqkv, wo, xb, xT, wqt, wk, wv, wob);

  // G_b = x_b^T x_b : lower triangle, split-K x4 (576 blocks, swizzled, 8 waves, dbuf)
  gemm_tri<<<576, 512, 0, stream>>>(xT, Gp);
  mirror_reduce<<<dim3(36, 4), 256, 0, stream>>>(Gp, G);

  // M partials directly: Mp[bh][es] = (wk_h @ G_b[e-slice]) @ wv_h-slice^T   (512 blocks)
  mdirect<<<512, 512, 0, stream>>>(wk, G, wv, Mp);

  // fused: reduce Mp -> Mt -> Amat_b = Wq^T * blockdiag(SCALE*M_b)   (512 blocks)
  amat_fused<<<dim3(8, 64), 256, 0, stream>>>(Mp, wqt, Amat);

  // Weff_b[j][e] = sum_i wo[j][i] * Amat_b[e][i]   (256 blocks, dbuf)
  gemm_bt<false><<<256, 512, 0, stream>>>(wob, 1024, 0, 0,
                                          Amat, 1024, M1, 0,
                                          (void*)Weff, 1024, M1, 0, 1024, 1, 8, 8);

  // out_b = x_b @ Weff_b^T  (fp32 out; 512 blocks, dbuf)
  gemm_bt<true><<<512, 512, 0, stream>>>(xb, 1024, 2048 * 1024L, 0,
                                         Weff, 1024, M1, 0,
                                         (void*)out, 1024, 2048 * 1024L, 0, 1024, 1, 8, 16);
}